// Round 3
// baseline (361.670 us; speedup 1.0000x reference)
//
#include <hip/hip_runtime.h>
#include <hip/hip_fp16.h>

#define USER_NUM 100000
#define ITEM_NUM 150000
#define N_NODES  250000
#define EMB      64
#define N_EDGES  1200000
#define N_ELEM   (N_NODES * EMB)   // 16,000,000

#define NBLK_E 512                 // histogram blocks (edge path)
#define NBUCK  245                 // ceil(N_NODES/1024) buckets of 1024 rows
#define INIT_BLOCKS 3907           // ceil(N_ELEM/16 / 256)
#define ROW_PAD 250944             // N_NODES padded to cover 245*1024=250880, 64-aligned

typedef float f4 __attribute__((ext_vector_type(4)));
typedef int   i4 __attribute__((ext_vector_type(4)));

// ------- phase 1 (fused): blocks [0,NBLK_E) per-row histogram; rest fp16 init -------
__global__ __launch_bounds__(256) void hist_init_kernel(
    const int* __restrict__ rows,
    int* __restrict__ row_cnt, int* __restrict__ bucket_cnt,
    const float* __restrict__ user, const float* __restrict__ item,
    __half* __restrict__ emb16)
{
    int t = threadIdx.x;

    if (blockIdx.x >= NBLK_E) {
        // ---- init path: 16 elems/thread, fp32 user||item -> fp16 table ----
        int gi = (blockIdx.x - NBLK_E) * 256 + t;
        if (gi < N_ELEM / 16) {
            int base = gi * 16;
            const int UE = USER_NUM * EMB;   // 6.4M, 16-aligned
            const f4* src = (base < UE) ? (const f4*)(user + base)
                                        : (const f4*)(item + (base - UE));
            f4 f0 = __builtin_nontemporal_load(src);
            f4 f1 = __builtin_nontemporal_load(src + 1);
            f4 f2 = __builtin_nontemporal_load(src + 2);
            f4 f3 = __builtin_nontemporal_load(src + 3);
            union { i4 v; __half2 h[4]; } a, b;
            a.h[0] = __float22half2_rn(make_float2(f0.x, f0.y));
            a.h[1] = __float22half2_rn(make_float2(f0.z, f0.w));
            a.h[2] = __float22half2_rn(make_float2(f1.x, f1.y));
            a.h[3] = __float22half2_rn(make_float2(f1.z, f1.w));
            b.h[0] = __float22half2_rn(make_float2(f2.x, f2.y));
            b.h[1] = __float22half2_rn(make_float2(f2.z, f2.w));
            b.h[2] = __float22half2_rn(make_float2(f3.x, f3.y));
            b.h[3] = __float22half2_rn(make_float2(f3.z, f3.w));
            ((i4*)(emb16 + base))[0] = a.v;
            ((i4*)(emb16 + base))[1] = b.v;
        }
        return;
    }

    // ---- histogram path: row counts (global, L2-resident) + bucket totals (LDS-agg) ----
    __shared__ int scnt[256];
    int b  = blockIdx.x;
    int e0 = (int)((long long)b * N_EDGES / NBLK_E);
    int e1 = (int)((long long)(b + 1) * N_EDGES / NBLK_E);

    scnt[t] = 0;
    __syncthreads();
    for (int e = e0 + t; e < e1; e += 256) {
        int r = rows[e];
        atomicAdd(&row_cnt[r], 1);
        atomicAdd(&scnt[r >> 10], 1);
    }
    __syncthreads();
    if (t < NBUCK && scnt[t] > 0) atomicAdd(&bucket_cnt[t], scnt[t]);
}

// ------- phase 2: two-level exclusive scan of 250K row counts -> row_ptr + cursors -------
// 245 blocks; each redundantly scans the 245 bucket totals (LDS), then scans its
// own 1024 counts. row_cnt pad is pre-zeroed, so loads past N_NODES read 0 and the
// row_ptr[N_NODES] = N_EDGES sentinel falls out of the scan naturally.
__global__ __launch_bounds__(256) void scan_kernel(
    const int* __restrict__ bucket_cnt,
    int* __restrict__ row_cnt,          // in: counts; out: scatter cursor (= row start)
    int* __restrict__ row_ptr)
{
    __shared__ int sb[256];
    __shared__ int sw[256];
    int t = threadIdx.x, b = blockIdx.x;

    int v = (t < NBUCK) ? bucket_cnt[t] : 0;
    sb[t] = v;
    __syncthreads();
    for (int off = 1; off < 256; off <<= 1) {
        int u = (t >= off) ? sb[t - off] : 0;
        __syncthreads();
        sb[t] += u;
        __syncthreads();
    }
    int bbase = (b == 0) ? 0 : sb[b - 1];

    int i0 = b * 1024 + 4 * t;              // max 250876+3 = 250879 < ROW_PAD
    i4 c = *(const i4*)(row_cnt + i0);
    int sum = c.x + c.y + c.z + c.w;
    sw[t] = sum;
    __syncthreads();
    for (int off = 1; off < 256; off <<= 1) {
        int u = (t >= off) ? sw[t - off] : 0;
        __syncthreads();
        sw[t] += u;
        __syncthreads();
    }
    int base = bbase + sw[t] - sum;

    i4 o;
    o.x = base;
    o.y = base + c.x;
    o.z = base + c.x + c.y;
    o.w = base + c.x + c.y + c.z;
    *(i4*)(row_ptr + i0) = o;               // idx N_NODES gets N_EDGES naturally
    *(i4*)(row_cnt + i0) = o;               // cursor init (in-place)
}

// ------- phase 3: scatter edges into CSR slots -------
__global__ __launch_bounds__(256) void scatter_kernel(
    const int* __restrict__ rows, const int* __restrict__ cols,
    const float* __restrict__ vals,
    int* __restrict__ cursor, int2* __restrict__ edges)
{
    int e = blockIdx.x * 256 + threadIdx.x;
    if (e < N_EDGES) {
        int r    = rows[e];
        int cv   = cols[e];
        float vv = vals[e];
        int slot = atomicAdd(&cursor[r], 1);
        edges[slot] = make_int2(cv, __float_as_int(vv));
    }
}

// ---------------- fused SpMM: quarter-wave (16 lanes) per row, ILP-8 ----------------
// Lane l owns dims [4l, 4l+4). MODE 0: cur_out = acc (fp16).
// MODE 1 (last layer): out = emb16[r] + cur1[r] + in16[r] + acc (fp32 store).
template <int MODE>
__global__ __launch_bounds__(256) void spmm_kernel(
    const int* __restrict__ row_ptr, const int2* __restrict__ edges,
    const __half* __restrict__ in16, const __half* __restrict__ emb16,
    const __half* __restrict__ cur1,
    float* __restrict__ out, __half* __restrict__ cur_out)
{
    int t = blockIdx.x * blockDim.x + threadIdx.x;
    int r = t >> 4;
    int l = t & 15;
    if (r >= N_NODES) return;
    int start = row_ptr[r];
    int end   = row_ptr[r + 1];
    int idx   = r * EMB + 4 * l;

    // prefetch epilogue terms (latency hides under the gather loop)
    union { int2 i; __half2 h[2]; } pe, p1, p2;
    if (MODE == 1) {
        pe.i = *(const int2*)(emb16 + idx);
        p1.i = *(const int2*)(cur1 + idx);
        p2.i = *(const int2*)(in16 + idx);
    }

    float ax = 0.f, ay = 0.f, az = 0.f, aw = 0.f;
    for (int j = start; j < end; j += 8) {
        int2 e[8];
#pragma unroll
        for (int k = 0; k < 8; ++k) e[k] = edges[j + k];   // pad-read past end ok
#pragma unroll
        for (int k = 0; k < 8; ++k) {
            bool ok = (j + k < end);
            int   c = ok ? e[k].x : 0;
            float v = ok ? __int_as_float(e[k].y) : 0.0f;
            union { int2 i; __half2 h[2]; } g;
            g.i = *(const int2*)(in16 + c * EMB + 4 * l);
            float2 x0 = __half22float2(g.h[0]);
            float2 x1 = __half22float2(g.h[1]);
            ax += v * x0.x; ay += v * x0.y;
            az += v * x1.x; aw += v * x1.y;
        }
    }

    if (MODE == 0) {
        union { int2 i; __half2 h[2]; } o;
        o.h[0] = __float22half2_rn(make_float2(ax, ay));
        o.h[1] = __float22half2_rn(make_float2(az, aw));
        *(int2*)(cur_out + idx) = o.i;
    } else {
        float2 e0 = __half22float2(pe.h[0]), e1 = __half22float2(pe.h[1]);
        float2 c0 = __half22float2(p1.h[0]), c1 = __half22float2(p1.h[1]);
        float2 d0 = __half22float2(p2.h[0]), d1 = __half22float2(p2.h[1]);
        float4 o = make_float4(e0.x + c0.x + d0.x + ax,
                               e0.y + c0.y + d0.y + ay,
                               e1.x + c1.x + d1.x + az,
                               e1.y + c1.y + d1.y + aw);
        *(float4*)(out + idx) = o;
    }
}

extern "C" void kernel_launch(void* const* d_in, const int* in_sizes, int n_in,
                              void* d_out, int out_size, void* d_ws, size_t ws_size,
                              hipStream_t stream) {
    const float* user = (const float*)d_in[0];
    const float* item = (const float*)d_in[1];
    const int*   rows = (const int*)d_in[2];
    const int*   cols = (const int*)d_in[3];
    const float* vals = (const float*)d_in[4];
    float*       out  = (float*)d_out;

    // workspace layout (256B aligned), ~108 MB total
    char* p = (char*)d_ws;
    __half* emb16   = (__half*)p;  p += (size_t)N_ELEM * 2;             // 32 MB
    __half* cur1    = (__half*)p;  p += (size_t)N_ELEM * 2;             // 32 MB
    __half* cur2    = (__half*)p;  p += (size_t)N_ELEM * 2;             // 32 MB
    int2*   edges   = (int2*)p;    p += (size_t)(N_EDGES + 32) * 8;     // 9.6 MB + pad
    int*    row_ptr = (int*)p;     p += (size_t)ROW_PAD * 4;            // 1.0 MB
    int*    row_cnt = (int*)p;     p += (size_t)ROW_PAD * 4;            // 1.0 MB (memset)
    int*    bucket_cnt = (int*)p;  p += 4096;                           // (memset)

    // zero row counts (incl. pad, so scan reads 0 past N_NODES) + bucket totals
    hipMemsetAsync(row_cnt, 0, (size_t)ROW_PAD * 4 + 4096, stream);

    hist_init_kernel<<<NBLK_E + INIT_BLOCKS, 256, 0, stream>>>(
        rows, row_cnt, bucket_cnt, user, item, emb16);
    scan_kernel<<<NBUCK, 256, 0, stream>>>(bucket_cnt, row_cnt, row_ptr);
    scatter_kernel<<<(N_EDGES + 255) / 256, 256, 0, stream>>>(
        rows, cols, vals, row_cnt, edges);

    const int spmm_blocks = (N_NODES * 16 + 255) / 256;   // 15625
    spmm_kernel<0><<<spmm_blocks, 256, 0, stream>>>(row_ptr, edges, emb16, emb16, cur1, out, cur1);
    spmm_kernel<0><<<spmm_blocks, 256, 0, stream>>>(row_ptr, edges, cur1, emb16, cur1, out, cur2);
    spmm_kernel<1><<<spmm_blocks, 256, 0, stream>>>(row_ptr, edges, cur2, emb16, cur1, out, nullptr);
}